// Round 12
// baseline (87.365 us; speedup 1.0000x reference)
//
#include <hip/hip_runtime.h>
#include <hip/hip_bf16.h>

using short8 = __attribute__((ext_vector_type(8))) short;
using f32x4  = __attribute__((ext_vector_type(4))) float;

constexpr int BSZ = 8192;
constexpr int DD  = 512;
constexpr int NC  = 100;
constexpr int NT  = 64;                 // 128-row tiles per dim
constexpr int NBLK = NT * (NT + 1) / 2; // 2080 upper-triangle blocks (= 8*260)
constexpr float INV_T = 1.0f / 0.07f;   // analytic row max = 1/T (diagonal)

static __device__ __forceinline__ ushort f2bf(float x) {
    union { float f; unsigned u; } c; c.f = x;
    unsigned r = c.u + 0x7fffu + ((c.u >> 16) & 1u);   // RNE
    return (ushort)(r >> 16);
}

static __device__ __forceinline__ void gload16(const void* g, void* l) {
    __builtin_amdgcn_global_load_lds((const __attribute__((address_space(1))) void*)g,
                                     (__attribute__((address_space(3))) void*)l, 16, 0, 0);
}

// asm ds_read_b128: opaque to compiler waitcnt insertion (counted pipeline survives)
#define DSR(dst, addr, imm) \
    asm volatile("ds_read_b128 %0, %1 offset:%2" : "=v"(dst) : "v"(addr), "i"(imm));

#define DPPADD(v, ctrl) { \
    int _x = __builtin_amdgcn_update_dpp(0, __float_as_int(v), ctrl, 0xf, 0xf, true); \
    v += __int_as_float(_x); }
#define ROWSUM16(v) { DPPADD(v, 0x128) DPPADD(v, 0x124) DPPADD(v, 0x122) DPPADD(v, 0x121) }

// ---------- kernel 1: L2-normalize rows, fp32 -> bf16 ----------
__global__ __launch_bounds__(256) void norm_rows(const float* __restrict__ feat,
                                                 ushort* __restrict__ fnrm) {
    const int row = blockIdx.x * 4 + (threadIdx.x >> 6);
    const int l   = threadIdx.x & 63;
    const float4* src = reinterpret_cast<const float4*>(feat + (size_t)row * DD);
    float4 v0 = src[l * 2 + 0];
    float4 v1 = src[l * 2 + 1];
    float ss = v0.x*v0.x + v0.y*v0.y + v0.z*v0.z + v0.w*v0.w
             + v1.x*v1.x + v1.y*v1.y + v1.z*v1.z + v1.w*v1.w;
    #pragma unroll
    for (int m = 32; m >= 1; m >>= 1) ss += __shfl_xor(ss, m, 64);
    const float rn = rsqrtf(ss);
    float vals[8] = {v0.x, v0.y, v0.z, v0.w, v1.x, v1.y, v1.z, v1.w};
    ushort u[8];
    #pragma unroll
    for (int j = 0; j < 8; ++j) u[j] = f2bf(vals[j] * rn);
    *reinterpret_cast<short8*>(fnrm + (size_t)row * DD + l * 8) =
        *reinterpret_cast<short8*>(u);
}

// ---------- kernel 2: label histogram (1 block; npos_i = hist[label_i]-1) ----------
__global__ __launch_bounds__(256) void label_hist(const int* __restrict__ labels,
                                                  int* __restrict__ counts) {
    __shared__ int lc[NC];
    const int t = threadIdx.x;
    if (t < NC) lc[t] = 0;
    __syncthreads();
    for (int i = t; i < BSZ; i += 256) atomicAdd(&lc[labels[i]], 1);
    __syncthreads();
    if (t < NC) counts[t] = lc[t];
}

// ---------- kernel 3: fused sim-GEMM, 128^2, upper-tri, 4 blocks/CU ----------
// 4 waves (2x2), wave = 64x64 out (acc[4][4] = 64 AGPR). BK=32, 16 K-tiles.
// 2 LDS bufs (32 KB) -> 4 blocks/CU (16 waves = 4/SIMD doing the latency
// hiding). Per iter: vmcnt(0)+barrier (tile it landed; issued one FULL iter
// ago) -> STG(it+1, buf^1) -> 8 ds_read -> lgkm0 -> 16 MFMA.
__global__ __launch_bounds__(256, 4) void supcon_main(const ushort* __restrict__ fnrm,
                                                      const int* __restrict__ labels,
                                                      float* __restrict__ part_denom,
                                                      float* __restrict__ part_spos) {
    __shared__ __align__(16) ushort smem[2 * 8192];    // 32 KB: buf b at b*16384B
    __shared__ int lbl_row[128], lbl_col[128];

    // bijective XCD-contiguous swizzle (2080 = 8 * 260) + upper-tri decode
    const int raw = blockIdx.x;
    const int bid = (raw & 7) * 260 + (raw >> 3);
    int rt = 0, rem = bid;
    while (rem >= NT - rt) { rem -= NT - rt; ++rt; }
    const int ct = rt + rem;
    const bool diag = (ct == rt);

    const int t  = threadIdx.x;
    const int l  = t & 63;
    const int lr = l & 15, grp = l >> 4;
    const int w  = t >> 6;
    const int wr = w >> 1, wc = w & 1;    // 2x2 wave grid; wave = 64x64 out
    const int rowBase = rt * 128, colBase = ct * 128;

    if (t < 128) { lbl_row[t] = labels[rowBase + t]; lbl_col[t] = labels[colBase + t]; }
    __syncthreads();                      // drain label traffic before pipeline

    // staging: thread t fills phys chunk t (rows 0-63) and t+256 (rows 64-127).
    // logical chunk = pc ^ ((row>>1)&3), invariant under row+64; applied by
    // pre-swizzling the global source (LDS dest stays linear).
    const int srow = t >> 2;
    const int slc  = (t & 3) ^ ((srow >> 1) & 3);
    const ushort* gA = fnrm + (size_t)(rowBase + srow) * DD + slc * 8;
    const ushort* gB = fnrm + (size_t)(colBase + srow) * DD + slc * 8;
    char* S = (char*)smem;
    const int t16 = t * 16;

    #define STG(kt, b) { \
        gload16(gA + (kt) * 32,           S + (b) * 16384 +         t16); \
        gload16(gA + (kt) * 32 + 64 * DD, S + (b) * 16384 +  4096 + t16); \
        gload16(gB + (kt) * 32,           S + (b) * 16384 +  8192 + t16); \
        gload16(gB + (kt) * 32 + 64 * DD, S + (b) * 16384 + 12288 + t16); }

    // ds_read byte addrs (loop-invariant); buf & frag are immediates.
    const int swz = ((grp ^ ((lr >> 1) & 3)) << 4);
    const int va  = (wr * 64 + lr) * 64 + swz;          // + b*16384 + fa*1024
    const int vb  = 8192 + (wc * 64 + lr) * 64 + swz;   // + b*16384 + fb*1024

    f32x4 acc[4][4];
    #pragma unroll
    for (int i = 0; i < 4; ++i)
        #pragma unroll
        for (int j = 0; j < 4; ++j) acc[i][j] = f32x4{0.f, 0.f, 0.f, 0.f};

    STG(0, 0)

    #pragma unroll
    for (int it = 0; it < 16; ++it) {
        const int b = it & 1;
        asm volatile("s_waitcnt vmcnt(0)" ::: "memory");  // tile it landed (own loads)
        __builtin_amdgcn_s_barrier();                     // all waves' loads landed
        if (it < 15) STG(it + 1, b ^ 1)                   // full-iter issue->wait gap

        short8 aF[4], bF[4];
        DSR(aF[0], va, (b * 16384) + 0)     DSR(aF[1], va, (b * 16384) + 1024)
        DSR(aF[2], va, (b * 16384) + 2048)  DSR(aF[3], va, (b * 16384) + 3072)
        DSR(bF[0], vb, (b * 16384) + 0)     DSR(bF[1], vb, (b * 16384) + 1024)
        DSR(bF[2], vb, (b * 16384) + 2048)  DSR(bF[3], vb, (b * 16384) + 3072)
        asm volatile("s_waitcnt lgkmcnt(0)");
        __builtin_amdgcn_sched_barrier(0);   // rule #18
        __builtin_amdgcn_s_setprio(1);
        #pragma unroll
        for (int fa = 0; fa < 4; ++fa)
            #pragma unroll
            for (int fb = 0; fb < 4; ++fb)
                acc[fa][fb] = __builtin_amdgcn_mfma_f32_16x16x32_bf16(
                    aF[fa], bF[fb], acc[fa][fb], 0, 0, 0);
        __builtin_amdgcn_s_setprio(0);
    }
    #undef STG

    // ---- epilogue: dual-side masked reduction (row + col partials) ----
    __syncthreads();
    float* red  = reinterpret_cast<float*>(smem);          // [128 row][2 wc][2]
    float* cred = reinterpret_cast<float*>(smem) + 512;    // [128 col][2 wr][2]

    int lcol[4];
    #pragma unroll
    for (int fb = 0; fb < 4; ++fb) lcol[fb] = lbl_col[wc * 64 + fb * 16 + lr];

    float cdv[4] = {0.f, 0.f, 0.f, 0.f}, csv[4] = {0.f, 0.f, 0.f, 0.f};
    #pragma unroll
    for (int fa = 0; fa < 4; ++fa) {
        #pragma unroll
        for (int r = 0; r < 4; ++r) {
            const int row_l = wr * 64 + fa * 16 + grp * 4 + r;
            const int grow  = rowBase + row_l;
            const int lrow  = lbl_row[row_l];
            float dsum = 0.f, ssum = 0.f;
            #pragma unroll
            for (int fb = 0; fb < 4; ++fb) {
                const int col_l = wc * 64 + fb * 16 + lr;
                const float sim = acc[fa][fb][r] * INV_T;
                const float e   = __expf(sim - INV_T);
                const bool  ok  = (colBase + col_l) != grow;   // self (diag only)
                const bool  pos = (lcol[fb] == lrow);
                const float ev  = ok ? e : 0.f;
                const float sv  = (ok && pos) ? sim : 0.f;
                dsum += ev; ssum += sv;
                cdv[fb] += ev; csv[fb] += sv;
            }
            ROWSUM16(dsum)
            ROWSUM16(ssum)
            if (lr == 0) {
                red[(row_l * 2 + wc) * 2 + 0] = dsum;
                red[(row_l * 2 + wc) * 2 + 1] = ssum;
            }
        }
    }
    #pragma unroll
    for (int fb = 0; fb < 4; ++fb) {      // col-side: reduce over grp lanes
        cdv[fb] += __shfl_xor(cdv[fb], 16, 64); cdv[fb] += __shfl_xor(cdv[fb], 32, 64);
        csv[fb] += __shfl_xor(csv[fb], 16, 64); csv[fb] += __shfl_xor(csv[fb], 32, 64);
    }
    if (grp == 0) {
        #pragma unroll
        for (int fb = 0; fb < 4; ++fb) {
            const int col_l = wc * 64 + fb * 16 + lr;
            cred[(col_l * 2 + wr) * 2 + 0] = cdv[fb];
            cred[(col_l * 2 + wr) * 2 + 1] = csv[fb];
        }
    }
    __syncthreads();
    if (t < 128) {                        // row-side: combine 2 wc halves
        const float d = red[(t * 2) * 2] + red[(t * 2 + 1) * 2];
        const float s = red[(t * 2) * 2 + 1] + red[(t * 2 + 1) * 2 + 1];
        part_denom[(size_t)ct * BSZ + rowBase + t] = d;
        part_spos [(size_t)ct * BSZ + rowBase + t] = s;
    } else if (!diag) {                   // col-side: combine 2 wr halves
        const int c = t - 128;
        const float d = cred[(c * 2) * 2] + cred[(c * 2 + 1) * 2];
        const float s = cred[(c * 2) * 2 + 1] + cred[(c * 2 + 1) * 2 + 1];
        part_denom[(size_t)rt * BSZ + colBase + c] = d;
        part_spos [(size_t)rt * BSZ + colBase + c] = s;
    }
}

// ---------- kernel 4: per-row finalize ----------
__global__ __launch_bounds__(256) void row_finalize(const float* __restrict__ part_denom,
                                                    const float* __restrict__ part_spos,
                                                    const int* __restrict__ counts,
                                                    const int* __restrict__ labels,
                                                    float* __restrict__ c_row,
                                                    float* __restrict__ v_row) {
    const int row = blockIdx.x * 256 + threadIdx.x;
    float denom = 0.f, spos = 0.f;
    for (int ctile = 0; ctile < NT; ++ctile) {
        denom += part_denom[(size_t)ctile * BSZ + row];
        spos  += part_spos [(size_t)ctile * BSZ + row];
    }
    const int   npos  = counts[labels[row]] - 1;
    const float npf   = (float)npos;
    const float mean  = (spos - npf * INV_T - npf * logf(denom + 1e-12f)) / (npf + 1e-12f);
    const bool  valid = npos > 0;
    c_row[row] = valid ? mean : 0.f;
    v_row[row] = valid ? 1.f : 0.f;
}

// ---------- kernel 5: final scalar reduce ----------
__global__ __launch_bounds__(1024) void final_reduce(const float* __restrict__ c_row,
                                                     const float* __restrict__ v_row,
                                                     float* __restrict__ out) {
    __shared__ float sdata[16], vdata[16];
    const int t = threadIdx.x;
    float s = 0.f, v = 0.f;
    for (int i = t; i < BSZ; i += 1024) { s += c_row[i]; v += v_row[i]; }
    #pragma unroll
    for (int m = 32; m >= 1; m >>= 1) { s += __shfl_xor(s, m, 64); v += __shfl_xor(v, m, 64); }
    if ((t & 63) == 0) { sdata[t >> 6] = s; vdata[t >> 6] = v; }
    __syncthreads();
    if (t == 0) {
        float st = 0.f, vt = 0.f;
        #pragma unroll
        for (int i = 0; i < 16; ++i) { st += sdata[i]; vt += vdata[i]; }
        out[0] = -st / fmaxf(vt, 1.f);
    }
}

extern "C" void kernel_launch(void* const* d_in, const int* in_sizes, int n_in,
                              void* d_out, int out_size, void* d_ws, size_t ws_size,
                              hipStream_t stream) {
    const float* feat   = (const float*)d_in[0];
    const int*   labels = (const int*)d_in[1];
    float*       out    = (float*)d_out;

    char* ws = (char*)d_ws;
    ushort* fnrm       = (ushort*)ws;  ws += (size_t)BSZ * DD * 2;   // 8 MB bf16
    float*  part_denom = (float*)ws;   ws += (size_t)NT * BSZ * 4;   // 2 MB
    float*  part_spos  = (float*)ws;   ws += (size_t)NT * BSZ * 4;   // 2 MB
    int*    counts     = (int*)ws;     ws += 512;
    float*  c_row      = (float*)ws;   ws += BSZ * 4;
    float*  v_row      = (float*)ws;   ws += BSZ * 4;

    hipLaunchKernelGGL(norm_rows,    dim3(BSZ / 4), dim3(256),  0, stream, feat, fnrm);
    hipLaunchKernelGGL(label_hist,   dim3(1),       dim3(256),  0, stream, labels, counts);
    hipLaunchKernelGGL(supcon_main,  dim3(NBLK),    dim3(256),  0, stream,
                       fnrm, labels, part_denom, part_spos);
    hipLaunchKernelGGL(row_finalize, dim3(BSZ/256), dim3(256),  0, stream,
                       part_denom, part_spos, counts, labels, c_row, v_row);
    hipLaunchKernelGGL(final_reduce, dim3(1),       dim3(1024), 0, stream, c_row, v_row, out);
}

// Round 13
// 85.430 us; speedup vs baseline: 1.0227x; 1.0227x over previous
//
#include <hip/hip_runtime.h>
#include <hip/hip_bf16.h>

using short8 = __attribute__((ext_vector_type(8))) short;
using f32x4  = __attribute__((ext_vector_type(4))) float;

constexpr int BSZ = 8192;
constexpr int DD  = 512;
constexpr int NC  = 100;
constexpr int NTT = 32;                    // 256-row tiles per dim
constexpr int NB2 = NTT * (NTT + 1) / 2;   // 528 upper-triangle blocks (= 8*66)
constexpr float INV_T = 1.0f / 0.07f;      // analytic shift m = 1/T

static __device__ __forceinline__ ushort f2bf(float x) {
    union { float f; unsigned u; } c; c.f = x;
    unsigned r = c.u + 0x7fffu + ((c.u >> 16) & 1u);   // RNE
    return (ushort)(r >> 16);
}
static __device__ __forceinline__ float bf2f(ushort u) {
    union { unsigned u; float f; } c; c.u = ((unsigned)u) << 16; return c.f;
}

static __device__ __forceinline__ void gload16(const void* g, void* l) {
    __builtin_amdgcn_global_load_lds((const __attribute__((address_space(1))) void*)g,
                                     (__attribute__((address_space(3))) void*)l, 16, 0, 0);
}

#define DSR(dst, addr, imm) \
    asm volatile("ds_read_b128 %0, %1 offset:%2" : "=v"(dst) : "v"(addr), "i"(imm));

#define DPPADD(v, ctrl) { \
    int _x = __builtin_amdgcn_update_dpp(0, __float_as_int(v), ctrl, 0xf, 0xf, true); \
    v += __int_as_float(_x); }
#define ROWSUM16(v) { DPPADD(v, 0x128) DPPADD(v, 0x124) DPPADD(v, 0x122) DPPADD(v, 0x121) }

// ---------- kernel 1: L2-normalize rows, fp32 -> bf16 ----------
__global__ __launch_bounds__(256) void norm_rows(const float* __restrict__ feat,
                                                 ushort* __restrict__ fnrm) {
    const int row = blockIdx.x * 4 + (threadIdx.x >> 6);
    const int l   = threadIdx.x & 63;
    const float4* src = reinterpret_cast<const float4*>(feat + (size_t)row * DD);
    float4 v0 = src[l * 2 + 0];
    float4 v1 = src[l * 2 + 1];
    float ss = v0.x*v0.x + v0.y*v0.y + v0.z*v0.z + v0.w*v0.w
             + v1.x*v1.x + v1.y*v1.y + v1.z*v1.z + v1.w*v1.w;
    #pragma unroll
    for (int m = 32; m >= 1; m >>= 1) ss += __shfl_xor(ss, m, 64);
    const float rn = rsqrtf(ss);
    float vals[8] = {v0.x, v0.y, v0.z, v0.w, v1.x, v1.y, v1.z, v1.w};
    ushort u[8];
    #pragma unroll
    for (int j = 0; j < 8; ++j) u[j] = f2bf(vals[j] * rn);
    *reinterpret_cast<short8*>(fnrm + (size_t)row * DD + l * 8) =
        *reinterpret_cast<short8*>(u);
}

// ---------- kernel 2: per-class g_c via ballot scan -> cls_val[c], counts[c] ----
// 100 blocks (one per class) x 256 thr. Labels staged to LDS once; each wave
// scans 2048 labels with 64-wide ballot; matching rows (~82 total) accumulate
// into per-lane fp32 partials (lane owns 8 dims). Deterministic (fixed order).
__global__ __launch_bounds__(256) void gsum(const ushort* __restrict__ fnrm,
                                            const int* __restrict__ labels,
                                            float* __restrict__ cls_val,
                                            int* __restrict__ counts) {
    __shared__ int   slab[BSZ];          // 32 KB
    __shared__ float gred[4][DD];        // 8 KB
    __shared__ float sq4[4];
    __shared__ int   cc[4];

    const int t = threadIdx.x, w = t >> 6, lam = t & 63;
    for (int i = t; i < BSZ; i += 256) slab[i] = labels[i];
    __syncthreads();

    const int c = blockIdx.x;
    float a[8] = {0.f,0.f,0.f,0.f,0.f,0.f,0.f,0.f};
    int cnt = 0;
    for (int base = w * 2048; base < (w + 1) * 2048; base += 64) {
        const unsigned long long m0 = __ballot(slab[base + lam] == c);
        cnt += (int)__popcll(m0);
        unsigned long long m = m0;
        while (m) {
            const int j = __ffsll((long long)m) - 1; m &= m - 1;
            const short8 v = *reinterpret_cast<const short8*>(
                fnrm + (size_t)(base + j) * DD + lam * 8);
            #pragma unroll
            for (int d = 0; d < 8; ++d) a[d] += bf2f((ushort)v[d]);
        }
    }
    #pragma unroll
    for (int d = 0; d < 8; ++d) gred[w][lam * 8 + d] = a[d];
    if (lam == 0) cc[w] = cnt;
    __syncthreads();

    const float g0 = gred[0][t] + gred[1][t] + gred[2][t] + gred[3][t];
    const float g1 = gred[0][t + 256] + gred[1][t + 256] + gred[2][t + 256] + gred[3][t + 256];
    float sq = g0 * g0 + g1 * g1;
    #pragma unroll
    for (int m = 32; m >= 1; m >>= 1) sq += __shfl_xor(sq, m, 64);
    if (lam == 0) sq4[w] = sq;
    __syncthreads();
    if (t == 0) {
        const float gsq = sq4[0] + sq4[1] + sq4[2] + sq4[3];
        const int   n   = cc[0] + cc[1] + cc[2] + cc[3];
        counts[c]  = n;
        cls_val[c] = (n >= 2) ? (gsq - (float)n) * INV_T / (float)(n - 1) : 0.f;
    }
}

// ---------- kernel 3: sim-GEMM -> denom only. 256^2, 8 waves, 4-phase/K-tile ----
// Waves 2Mr x 4Nc, wave tile 128x64, acc[8][4]=128 regs. BK=64, 8 iters, 2 LDS
// bufs (A 32K + B 32K each). Per phase: {4-8 ds_read || 4 gloads} barrier,
// lgkm0, sched_barrier, setprio, 16 MFMA, barrier. vmcnt(0) once per iter.
__global__ __launch_bounds__(512, 2) void supcon_main(const ushort* __restrict__ fnrm,
                                                      float* __restrict__ part_denom) {
    __shared__ __align__(16) ushort smem[2 * 32768];   // 128 KB

    const int raw = blockIdx.x;                         // XCD swizzle (528 = 8*66)
    const int bid = (raw & 7) * 66 + (raw >> 3);
    int rt = 0, rem = bid;
    while (rem >= NTT - rt) { rem -= NTT - rt; ++rt; }
    const int ct = rt + rem;
    const bool diag = (ct == rt);

    const int t  = threadIdx.x;
    const int l  = t & 63;
    const int lr = l & 15, grp = l >> 4;
    const int w  = t >> 6;
    const int wr = w >> 2, wc = w & 3;    // 2Mr x 4Nc; wave = 128x64 out
    const int rowBase = rt * 256, colBase = ct * 256;

    // staging: thread t owns 16B chunk row=(t>>3)+j*64, phys chunk pc=t&7 of
    // each [256][8-chunk] tile; logical chunk = pc ^ (row&7) = (t&7)^((t>>3)&7)
    // (invariant under row+64). Pre-swizzled global source; LDS dest linear.
    const int srow = t >> 3;
    const int slc  = (t & 7) ^ (srow & 7);
    const ushort* gA1 = fnrm + (size_t)(rowBase + srow) * DD + slc * 8;
    const ushort* gB1 = fnrm + (size_t)(colBase + srow) * DD + slc * 8;
    char* S = (char*)smem;
    const int t16 = t * 16;

    // ds_read base addrs (+ b*65536 at use; fa/fb add imm*2048, fa4-7 +8192)
    const int va_k0 = (wr * 128 + lr) * 128 + (((0 + grp) ^ (lr & 7)) << 4);
    const int va_k1 = (wr * 128 + lr) * 128 + (((4 + grp) ^ (lr & 7)) << 4);
    const int vb_k0 = 32768 + (wc * 64 + lr) * 128 + (((0 + grp) ^ (lr & 7)) << 4);
    const int vb_k1 = 32768 + (wc * 64 + lr) * 128 + (((4 + grp) ^ (lr & 7)) << 4);

    f32x4 acc[8][4];
    #pragma unroll
    for (int i = 0; i < 8; ++i)
        #pragma unroll
        for (int j = 0; j < 4; ++j) acc[i][j] = f32x4{0.f, 0.f, 0.f, 0.f};

    #define STGA(kt, boff) { \
        gload16(gA1 + (kt) * 64,            S + (boff) +         t16); \
        gload16(gA1 + (kt) * 64 +  64 * DD, S + (boff) +  8192 + t16); \
        gload16(gA1 + (kt) * 64 + 128 * DD, S + (boff) + 16384 + t16); \
        gload16(gA1 + (kt) * 64 + 192 * DD, S + (boff) + 24576 + t16); }
    #define STGB(kt, boff) { \
        gload16(gB1 + (kt) * 64,            S + (boff) + 32768 + t16); \
        gload16(gB1 + (kt) * 64 +  64 * DD, S + (boff) + 40960 + t16); \
        gload16(gB1 + (kt) * 64 + 128 * DD, S + (boff) + 49152 + t16); \
        gload16(gB1 + (kt) * 64 + 192 * DD, S + (boff) + 57344 + t16); }

    #define MFMA16(H) { \
        _Pragma("unroll") \
        for (int fa = 0; fa < 4; ++fa) \
            _Pragma("unroll") \
            for (int fb = 0; fb < 4; ++fb) \
                acc[(H) * 4 + fa][fb] = __builtin_amdgcn_mfma_f32_16x16x32_bf16( \
                    aF[fa], bF[fb], acc[(H) * 4 + fa][fb], 0, 0, 0); }

    #define PH_TAIL() \
        __builtin_amdgcn_s_barrier(); \
        asm volatile("s_waitcnt lgkmcnt(0)"); \
        __builtin_amdgcn_sched_barrier(0); \
        __builtin_amdgcn_s_setprio(1);
    #define PH_END() \
        __builtin_amdgcn_sched_barrier(0); \
        __builtin_amdgcn_s_setprio(0); \
        __builtin_amdgcn_s_barrier();

    STGA(0, 0) STGB(0, 0)                 // prologue: tile 0 -> buf 0

    #pragma unroll
    for (int it = 0; it < 8; ++it) {
        const int boff = (it & 1) << 16, nboff = boff ^ 65536;
        asm volatile("s_waitcnt vmcnt(0)" ::: "memory");  // tile it landed
        __builtin_amdgcn_s_barrier();

        short8 aF[4], bF[4];
        {   // phase 0: ks0, fa0-3 + B(ks0); stage A of tile it+1
            const int aa = va_k0 + boff, bb = vb_k0 + boff;
            DSR(aF[0], aa, 0) DSR(aF[1], aa, 2048) DSR(aF[2], aa, 4096) DSR(aF[3], aa, 6144)
            DSR(bF[0], bb, 0) DSR(bF[1], bb, 2048) DSR(bF[2], bb, 4096) DSR(bF[3], bb, 6144)
            if (it < 7) STGA(it + 1, nboff)
            PH_TAIL() MFMA16(0) PH_END()
        }
        {   // phase 1: ks0, fa4-7 (reuse bF); stage B of tile it+1
            const int aa = va_k0 + boff;
            DSR(aF[0], aa, 8192) DSR(aF[1], aa, 10240) DSR(aF[2], aa, 12288) DSR(aF[3], aa, 14336)
            if (it < 7) STGB(it + 1, nboff)
            PH_TAIL() MFMA16(1) PH_END()
        }
        {   // phase 2: ks1, fa0-3 + B(ks1)
            const int aa = va_k1 + boff, bb = vb_k1 + boff;
            DSR(aF[0], aa, 0) DSR(aF[1], aa, 2048) DSR(aF[2], aa, 4096) DSR(aF[3], aa, 6144)
            DSR(bF[0], bb, 0) DSR(bF[1], bb, 2048) DSR(bF[2], bb, 4096) DSR(bF[3], bb, 6144)
            PH_TAIL() MFMA16(0) PH_END()
        }
        {   // phase 3: ks1, fa4-7
            const int aa = va_k1 + boff;
            DSR(aF[0], aa, 8192) DSR(aF[1], aa, 10240) DSR(aF[2], aa, 12288) DSR(aF[3], aa, 14336)
            PH_TAIL() MFMA16(1) PH_END()
        }
    }
    #undef STGA
    #undef STGB

    // ---- lean epilogue: e = exp(sim - m); row & col denom sums only ----
    __syncthreads();
    float* red  = reinterpret_cast<float*>(smem);          // [256 row][4 wc]
    float* cred = reinterpret_cast<float*>(smem) + 1024;   // [256 col][2 wr]

    float cdv[4] = {0.f, 0.f, 0.f, 0.f};
    #pragma unroll
    for (int fa = 0; fa < 8; ++fa) {
        #pragma unroll
        for (int r = 0; r < 4; ++r) {
            const int row_l = wr * 128 + fa * 16 + grp * 4 + r;
            const int grow  = rowBase + row_l;
            float dsum = 0.f;
            #pragma unroll
            for (int fb = 0; fb < 4; ++fb) {
                const int col_l = wc * 64 + fb * 16 + lr;
                const float e  = __expf(acc[fa][fb][r] * INV_T - INV_T);
                const float ev = ((colBase + col_l) != grow) ? e : 0.f;
                dsum += ev; cdv[fb] += ev;
            }
            ROWSUM16(dsum)
            if (lr == 0) red[row_l * 4 + wc] = dsum;
        }
    }
    #pragma unroll
    for (int fb = 0; fb < 4; ++fb) {
        cdv[fb] += __shfl_xor(cdv[fb], 16, 64);
        cdv[fb] += __shfl_xor(cdv[fb], 32, 64);
    }
    if (grp == 0) {
        #pragma unroll
        for (int fb = 0; fb < 4; ++fb)
            cred[(wc * 64 + fb * 16 + lr) * 2 + wr] = cdv[fb];
    }
    __syncthreads();
    if (t < 256) {
        const float d = red[t*4] + red[t*4+1] + red[t*4+2] + red[t*4+3];
        part_denom[(size_t)ct * BSZ + rowBase + t] = d;
    } else if (!diag) {
        const int c = t - 256;
        const float d = cred[c*2] + cred[c*2+1];
        part_denom[(size_t)rt * BSZ + colBase + c] = d;
    }
}

// ---------- kernel 4: per-row lse + per-block scalar partials ----------
__global__ __launch_bounds__(256) void row_finalize(const float* __restrict__ part_denom,
                                                    const int* __restrict__ counts,
                                                    const int* __restrict__ labels,
                                                    float* __restrict__ bsum,
                                                    float* __restrict__ bval) {
    __shared__ float s4[4], v4[4];
    const int t = threadIdx.x;
    const int row = blockIdx.x * 256 + t;
    float denom = 0.f;
    for (int k = 0; k < NTT; ++k) denom += part_denom[(size_t)k * BSZ + row];
    const bool valid = counts[labels[row]] >= 2;
    float s = valid ? (INV_T + logf(denom + 1e-12f)) : 0.f;
    float v = valid ? 1.f : 0.f;
    #pragma unroll
    for (int m = 32; m >= 1; m >>= 1) { s += __shfl_xor(s, m, 64); v += __shfl_xor(v, m, 64); }
    if ((t & 63) == 0) { s4[t >> 6] = s; v4[t >> 6] = v; }
    __syncthreads();
    if (t == 0) {
        bsum[blockIdx.x] = s4[0] + s4[1] + s4[2] + s4[3];
        bval[blockIdx.x] = v4[0] + v4[1] + v4[2] + v4[3];
    }
}

// ---------- kernel 5: final scalar ----------
__global__ __launch_bounds__(128) void final_reduce(const float* __restrict__ bsum,
                                                    const float* __restrict__ bval,
                                                    const float* __restrict__ cls_val,
                                                    float* __restrict__ out) {
    __shared__ float r2[2], q2[2], p2[2];
    const int t = threadIdx.x;
    float s = (t < 32) ? bsum[t] : 0.f;
    float v = (t < 32) ? bval[t] : 0.f;
    float p = (t < NC) ? cls_val[t] : 0.f;
    #pragma unroll
    for (int m = 32; m >= 1; m >>= 1) {
        s += __shfl_xor(s, m, 64); v += __shfl_xor(v, m, 64); p += __shfl_xor(p, m, 64);
    }
    if ((t & 63) == 0) { r2[t >> 6] = s; q2[t >> 6] = v; p2[t >> 6] = p; }
    __syncthreads();
    if (t == 0) {
        const float S = r2[0] + r2[1], V = q2[0] + q2[1], SP = p2[0] + p2[1];
        out[0] = -(SP - S) / fmaxf(V, 1.f);
    }
}

extern "C" void kernel_launch(void* const* d_in, const int* in_sizes, int n_in,
                              void* d_out, int out_size, void* d_ws, size_t ws_size,
                              hipStream_t stream) {
    const float* feat   = (const float*)d_in[0];
    const int*   labels = (const int*)d_in[1];
    float*       out    = (float*)d_out;

    char* ws = (char*)d_ws;
    ushort* fnrm       = (ushort*)ws;  ws += (size_t)BSZ * DD * 2;   // 8 MB
    float*  part_denom = (float*)ws;   ws += (size_t)NTT * BSZ * 4;  // 1 MB
    float*  cls_val    = (float*)ws;   ws += NC * 4 + 288;
    int*    counts     = (int*)ws;     ws += NC * 4 + 288;
    float*  bsum       = (float*)ws;   ws += 32 * 4;
    float*  bval       = (float*)ws;   ws += 32 * 4;

    hipLaunchKernelGGL(norm_rows,    dim3(BSZ / 4), dim3(256),  0, stream, feat, fnrm);
    hipLaunchKernelGGL(gsum,         dim3(NC),      dim3(256),  0, stream,
                       fnrm, labels, cls_val, counts);
    hipLaunchKernelGGL(supcon_main,  dim3(NB2),     dim3(512),  0, stream,
                       fnrm, part_denom);
    hipLaunchKernelGGL(row_finalize, dim3(BSZ/256), dim3(256),  0, stream,
                       part_denom, counts, labels, bsum, bval);
    hipLaunchKernelGGL(final_reduce, dim3(1),       dim3(128),  0, stream,
                       bsum, bval, cls_val, out);
}

// Round 14
// 77.171 us; speedup vs baseline: 1.1321x; 1.1070x over previous
//
#include <hip/hip_runtime.h>
#include <hip/hip_bf16.h>

using short8 = __attribute__((ext_vector_type(8))) short;
using f32x4  = __attribute__((ext_vector_type(4))) float;

constexpr int BSZ = 8192;
constexpr int DD  = 512;
constexpr int NC  = 100;
constexpr int NT  = 64;                 // 128-row tiles per dim
constexpr int NBLK = NT * (NT + 1) / 2; // 2080 upper-triangle blocks (= 8*260)
constexpr float INV_T = 1.0f / 0.07f;   // analytic shift m = 1/T

static __device__ __forceinline__ ushort f2bf(float x) {
    union { float f; unsigned u; } c; c.f = x;
    unsigned r = c.u + 0x7fffu + ((c.u >> 16) & 1u);   // RNE
    return (ushort)(r >> 16);
}
static __device__ __forceinline__ float bf2f(ushort u) {
    union { unsigned u; float f; } c; c.u = ((unsigned)u) << 16; return c.f;
}

static __device__ __forceinline__ void gload16(const void* g, void* l) {
    __builtin_amdgcn_global_load_lds((const __attribute__((address_space(1))) void*)g,
                                     (__attribute__((address_space(3))) void*)l, 16, 0, 0);
}

// asm ds_read_b128: opaque to compiler waitcnt insertion (counted pipeline survives)
#define DSR(dst, addr, imm) \
    asm volatile("ds_read_b128 %0, %1 offset:%2" : "=v"(dst) : "v"(addr), "i"(imm));

#define DPPADD(v, ctrl) { \
    int _x = __builtin_amdgcn_update_dpp(0, __float_as_int(v), ctrl, 0xf, 0xf, true); \
    v += __int_as_float(_x); }
#define ROWSUM16(v) { DPPADD(v, 0x128) DPPADD(v, 0x124) DPPADD(v, 0x122) DPPADD(v, 0x121) }

// ---------- kernel 1: L2-normalize rows, fp32 -> bf16 ----------
__global__ __launch_bounds__(256) void norm_rows(const float* __restrict__ feat,
                                                 ushort* __restrict__ fnrm) {
    const int row = blockIdx.x * 4 + (threadIdx.x >> 6);
    const int l   = threadIdx.x & 63;
    const float4* src = reinterpret_cast<const float4*>(feat + (size_t)row * DD);
    float4 v0 = src[l * 2 + 0];
    float4 v1 = src[l * 2 + 1];
    float ss = v0.x*v0.x + v0.y*v0.y + v0.z*v0.z + v0.w*v0.w
             + v1.x*v1.x + v1.y*v1.y + v1.z*v1.z + v1.w*v1.w;
    #pragma unroll
    for (int m = 32; m >= 1; m >>= 1) ss += __shfl_xor(ss, m, 64);
    const float rn = rsqrtf(ss);
    float vals[8] = {v0.x, v0.y, v0.z, v0.w, v1.x, v1.y, v1.z, v1.w};
    ushort u[8];
    #pragma unroll
    for (int j = 0; j < 8; ++j) u[j] = f2bf(vals[j] * rn);
    *reinterpret_cast<short8*>(fnrm + (size_t)row * DD + l * 8) =
        *reinterpret_cast<short8*>(u);
}

// ---------- kernel 2: per-class g_c via ballot scan -> cls_val[c], counts[c] ----
// (verified R13) Sum_pos sim identity: sum_i spos_i/npos_i = (||g_c||^2-n)/(T(n-1))
__global__ __launch_bounds__(256) void gsum(const ushort* __restrict__ fnrm,
                                            const int* __restrict__ labels,
                                            float* __restrict__ cls_val,
                                            int* __restrict__ counts) {
    __shared__ int   slab[BSZ];          // 32 KB
    __shared__ float gred[4][DD];        // 8 KB
    __shared__ float sq4[4];
    __shared__ int   cc[4];

    const int t = threadIdx.x, w = t >> 6, lam = t & 63;
    for (int i = t; i < BSZ; i += 256) slab[i] = labels[i];
    __syncthreads();

    const int c = blockIdx.x;
    float a[8] = {0.f,0.f,0.f,0.f,0.f,0.f,0.f,0.f};
    int cnt = 0;
    for (int base = w * 2048; base < (w + 1) * 2048; base += 64) {
        const unsigned long long m0 = __ballot(slab[base + lam] == c);
        cnt += (int)__popcll(m0);
        unsigned long long m = m0;
        while (m) {
            const int j = __ffsll((long long)m) - 1; m &= m - 1;
            const short8 v = *reinterpret_cast<const short8*>(
                fnrm + (size_t)(base + j) * DD + lam * 8);
            #pragma unroll
            for (int d = 0; d < 8; ++d) a[d] += bf2f((ushort)v[d]);
        }
    }
    #pragma unroll
    for (int d = 0; d < 8; ++d) gred[w][lam * 8 + d] = a[d];
    if (lam == 0) cc[w] = cnt;
    __syncthreads();

    const float g0 = gred[0][t] + gred[1][t] + gred[2][t] + gred[3][t];
    const float g1 = gred[0][t + 256] + gred[1][t + 256] + gred[2][t + 256] + gred[3][t + 256];
    float sq = g0 * g0 + g1 * g1;
    #pragma unroll
    for (int m = 32; m >= 1; m >>= 1) sq += __shfl_xor(sq, m, 64);
    if (lam == 0) sq4[w] = sq;
    __syncthreads();
    if (t == 0) {
        const float gsq = sq4[0] + sq4[1] + sq4[2] + sq4[3];
        const int   n   = cc[0] + cc[1] + cc[2] + cc[3];
        counts[c]  = n;
        cls_val[c] = (n >= 2) ? (gsq - (float)n) * INV_T / (float)(n - 1) : 0.f;
    }
}

// ---------- kernel 3: sim-GEMM -> denom only. R11 loop + lean epilogue ----------
// 4 waves (2x2), wave = 64x64 out (acc[4][4] = 64 AGPR). BK=32, 16 K-tiles.
// 3 LDS bufs, depth-2 prefetch, counted vmcnt(4), ONE barrier/iter, 3 blocks/CU.
__global__ __launch_bounds__(256, 3) void supcon_main(const ushort* __restrict__ fnrm,
                                                      float* __restrict__ part_denom) {
    __shared__ __align__(16) ushort smem[3 * 8192];    // 48 KB: buf b at b*16384B

    // bijective XCD-contiguous swizzle (2080 = 8 * 260) + upper-tri decode
    const int raw = blockIdx.x;
    const int bid = (raw & 7) * 260 + (raw >> 3);
    int rt = 0, rem = bid;
    while (rem >= NT - rt) { rem -= NT - rt; ++rt; }
    const int ct = rt + rem;
    const bool diag = (ct == rt);

    const int t  = threadIdx.x;
    const int l  = t & 63;
    const int lr = l & 15, grp = l >> 4;
    const int w  = t >> 6;
    const int wr = w >> 1, wc = w & 1;    // 2x2 wave grid; wave = 64x64 out
    const int rowBase = rt * 128, colBase = ct * 128;

    // staging: thread t fills phys chunk t (rows 0-63) and t+256 (rows 64-127).
    // logical chunk = pc ^ ((row>>1)&3), invariant under row+64; applied by
    // pre-swizzling the global source (LDS dest stays linear).
    const int srow = t >> 2;
    const int slc  = (t & 3) ^ ((srow >> 1) & 3);
    const ushort* gA = fnrm + (size_t)(rowBase + srow) * DD + slc * 8;
    const ushort* gB = fnrm + (size_t)(colBase + srow) * DD + slc * 8;
    char* S = (char*)smem;
    const int t16 = t * 16;

    #define STG(kt, b) { \
        gload16(gA + (kt) * 32,           S + (b) * 16384 +         t16); \
        gload16(gA + (kt) * 32 + 64 * DD, S + (b) * 16384 +  4096 + t16); \
        gload16(gB + (kt) * 32,           S + (b) * 16384 +  8192 + t16); \
        gload16(gB + (kt) * 32 + 64 * DD, S + (b) * 16384 + 12288 + t16); }

    // ds_read byte addrs (loop-invariant); buf & frag are immediates.
    const int swz = ((grp ^ ((lr >> 1) & 3)) << 4);
    const int va  = (wr * 64 + lr) * 64 + swz;          // + b*16384 + fa*1024
    const int vb  = 8192 + (wc * 64 + lr) * 64 + swz;   // + b*16384 + fb*1024

    f32x4 acc[4][4];
    #pragma unroll
    for (int i = 0; i < 4; ++i)
        #pragma unroll
        for (int j = 0; j < 4; ++j) acc[i][j] = f32x4{0.f, 0.f, 0.f, 0.f};

    STG(0, 0)
    STG(1, 1)

    #pragma unroll
    for (int it = 0; it < 16; ++it) {
        const int b = it % 3;
        if (it < 15) { asm volatile("s_waitcnt vmcnt(4)" ::: "memory"); }
        else         { asm volatile("s_waitcnt vmcnt(0)" ::: "memory"); }
        __builtin_amdgcn_s_barrier();     // tile 'it' fully in LDS for all waves

        short8 aF[4], bF[4];
        DSR(aF[0], va, (b * 16384) + 0)     DSR(aF[1], va, (b * 16384) + 1024)
        DSR(aF[2], va, (b * 16384) + 2048)  DSR(aF[3], va, (b * 16384) + 3072)
        DSR(bF[0], vb, (b * 16384) + 0)     DSR(bF[1], vb, (b * 16384) + 1024)
        DSR(bF[2], vb, (b * 16384) + 2048)  DSR(bF[3], vb, (b * 16384) + 3072)
        if (it < 14) {
            const int nb = (it + 2) % 3;  // overwrites buf of tile it-1 (reads done)
            STG(it + 2, nb)
        }
        asm volatile("s_waitcnt lgkmcnt(0)");
        __builtin_amdgcn_sched_barrier(0);   // rule #18
        __builtin_amdgcn_s_setprio(1);
        #pragma unroll
        for (int fa = 0; fa < 4; ++fa)
            #pragma unroll
            for (int fb = 0; fb < 4; ++fb)
                acc[fa][fb] = __builtin_amdgcn_mfma_f32_16x16x32_bf16(
                    aF[fa], bF[fb], acc[fa][fb], 0, 0, 0);
        __builtin_amdgcn_s_setprio(0);
    }
    #undef STG

    // ---- lean epilogue: e = exp(sim - m); row & col denom sums only ----
    __syncthreads();
    float* red  = reinterpret_cast<float*>(smem);          // [128 row][2 wc]
    float* cred = reinterpret_cast<float*>(smem) + 256;    // [128 col][2 wr]

    float cdv[4] = {0.f, 0.f, 0.f, 0.f};
    #pragma unroll
    for (int fa = 0; fa < 4; ++fa) {
        #pragma unroll
        for (int r = 0; r < 4; ++r) {
            const int row_l = wr * 64 + fa * 16 + grp * 4 + r;
            const int grow  = rowBase + row_l;
            float dsum = 0.f;
            #pragma unroll
            for (int fb = 0; fb < 4; ++fb) {
                const int col_l = wc * 64 + fb * 16 + lr;
                const float e  = __expf(acc[fa][fb][r] * INV_T - INV_T);
                const float ev = ((colBase + col_l) != grow) ? e : 0.f;
                dsum += ev; cdv[fb] += ev;
            }
            ROWSUM16(dsum)
            if (lr == 0) red[row_l * 2 + wc] = dsum;
        }
    }
    #pragma unroll
    for (int fb = 0; fb < 4; ++fb) {      // col-side: reduce over grp lanes
        cdv[fb] += __shfl_xor(cdv[fb], 16, 64);
        cdv[fb] += __shfl_xor(cdv[fb], 32, 64);
    }
    if (grp == 0) {
        #pragma unroll
        for (int fb = 0; fb < 4; ++fb)
            cred[(wc * 64 + fb * 16 + lr) * 2 + wr] = cdv[fb];
    }
    __syncthreads();
    if (t < 128) {                        // row-side: combine 2 wc halves
        const float d = red[t * 2] + red[t * 2 + 1];
        part_denom[(size_t)ct * BSZ + rowBase + t] = d;
    } else if (!diag) {                   // col-side: combine 2 wr halves
        const int c = t - 128;
        const float d = cred[c * 2] + cred[c * 2 + 1];
        part_denom[(size_t)rt * BSZ + colBase + c] = d;
    }
}

// ---------- kernel 4: per-row lse + per-block scalar partials ----------
__global__ __launch_bounds__(256) void row_finalize(const float* __restrict__ part_denom,
                                                    const int* __restrict__ counts,
                                                    const int* __restrict__ labels,
                                                    float* __restrict__ bsum,
                                                    float* __restrict__ bval) {
    __shared__ float s4[4], v4[4];
    const int t = threadIdx.x;
    const int row = blockIdx.x * 256 + t;
    float denom = 0.f;
    for (int k = 0; k < NT; ++k) denom += part_denom[(size_t)k * BSZ + row];
    const bool valid = counts[labels[row]] >= 2;
    float s = valid ? (INV_T + logf(denom + 1e-12f)) : 0.f;
    float v = valid ? 1.f : 0.f;
    #pragma unroll
    for (int m = 32; m >= 1; m >>= 1) { s += __shfl_xor(s, m, 64); v += __shfl_xor(v, m, 64); }
    if ((t & 63) == 0) { s4[t >> 6] = s; v4[t >> 6] = v; }
    __syncthreads();
    if (t == 0) {
        bsum[blockIdx.x] = s4[0] + s4[1] + s4[2] + s4[3];
        bval[blockIdx.x] = v4[0] + v4[1] + v4[2] + v4[3];
    }
}

// ---------- kernel 5: final scalar ----------
__global__ __launch_bounds__(128) void final_reduce(const float* __restrict__ bsum,
                                                    const float* __restrict__ bval,
                                                    const float* __restrict__ cls_val,
                                                    float* __restrict__ out) {
    __shared__ float r2[2], q2[2], p2[2];
    const int t = threadIdx.x;
    float s = (t < 32) ? bsum[t] : 0.f;
    float v = (t < 32) ? bval[t] : 0.f;
    float p = (t < NC) ? cls_val[t] : 0.f;
    #pragma unroll
    for (int m = 32; m >= 1; m >>= 1) {
        s += __shfl_xor(s, m, 64); v += __shfl_xor(v, m, 64); p += __shfl_xor(p, m, 64);
    }
    if ((t & 63) == 0) { r2[t >> 6] = s; q2[t >> 6] = v; p2[t >> 6] = p; }
    __syncthreads();
    if (t == 0) {
        const float S = r2[0] + r2[1], V = q2[0] + q2[1], SP = p2[0] + p2[1];
        out[0] = -(SP - S) / fmaxf(V, 1.f);
    }
}

extern "C" void kernel_launch(void* const* d_in, const int* in_sizes, int n_in,
                              void* d_out, int out_size, void* d_ws, size_t ws_size,
                              hipStream_t stream) {
    const float* feat   = (const float*)d_in[0];
    const int*   labels = (const int*)d_in[1];
    float*       out    = (float*)d_out;

    char* ws = (char*)d_ws;
    ushort* fnrm       = (ushort*)ws;  ws += (size_t)BSZ * DD * 2;   // 8 MB
    float*  part_denom = (float*)ws;   ws += (size_t)NT * BSZ * 4;   // 2 MB
    float*  cls_val    = (float*)ws;   ws += NC * 4 + 288;
    int*    counts     = (int*)ws;     ws += NC * 4 + 288;
    float*  bsum       = (float*)ws;   ws += 32 * 4;
    float*  bval       = (float*)ws;   ws += 32 * 4;

    hipLaunchKernelGGL(norm_rows,    dim3(BSZ / 4), dim3(256),  0, stream, feat, fnrm);
    hipLaunchKernelGGL(gsum,         dim3(NC),      dim3(256),  0, stream,
                       fnrm, labels, cls_val, counts);
    hipLaunchKernelGGL(supcon_main,  dim3(NBLK),    dim3(256),  0, stream,
                       fnrm, part_denom);
    hipLaunchKernelGGL(row_finalize, dim3(BSZ/256), dim3(256),  0, stream,
                       part_denom, counts, labels, bsum, bval);
    hipLaunchKernelGGL(final_reduce, dim3(1),       dim3(128),  0, stream,
                       bsum, bval, cls_val, out);
}

// Round 15
// 76.383 us; speedup vs baseline: 1.1438x; 1.0103x over previous
//
#include <hip/hip_runtime.h>
#include <hip/hip_bf16.h>

using short8 = __attribute__((ext_vector_type(8))) short;
using f32x4  = __attribute__((ext_vector_type(4))) float;

constexpr int BSZ = 8192;
constexpr int DD  = 512;
constexpr int NC  = 100;
constexpr int NT  = 64;                 // 128-row tiles per dim
constexpr int NBLK = NT * (NT + 1) / 2; // 2080 upper-triangle blocks (= 8*260)
constexpr float INV_T = 1.0f / 0.07f;   // analytic shift m = 1/T

static __device__ __forceinline__ ushort f2bf(float x) {
    union { float f; unsigned u; } c; c.f = x;
    unsigned r = c.u + 0x7fffu + ((c.u >> 16) & 1u);   // RNE
    return (ushort)(r >> 16);
}
static __device__ __forceinline__ float bf2f(ushort u) {
    union { unsigned u; float f; } c; c.u = ((unsigned)u) << 16; return c.f;
}

static __device__ __forceinline__ void gload16(const void* g, void* l) {
    __builtin_amdgcn_global_load_lds((const __attribute__((address_space(1))) void*)g,
                                     (__attribute__((address_space(3))) void*)l, 16, 0, 0);
}

// asm ds_read_b128: opaque to compiler waitcnt insertion (counted pipeline survives)
#define DSR(dst, addr, imm) \
    asm volatile("ds_read_b128 %0, %1 offset:%2" : "=v"(dst) : "v"(addr), "i"(imm));

#define DPPADD(v, ctrl) { \
    int _x = __builtin_amdgcn_update_dpp(0, __float_as_int(v), ctrl, 0xf, 0xf, true); \
    v += __int_as_float(_x); }
#define ROWSUM16(v) { DPPADD(v, 0x128) DPPADD(v, 0x124) DPPADD(v, 0x122) DPPADD(v, 0x121) }

// ---------- kernel 1: L2-normalize rows, fp32 -> bf16 ----------
__global__ __launch_bounds__(256) void norm_rows(const float* __restrict__ feat,
                                                 ushort* __restrict__ fnrm) {
    const int row = blockIdx.x * 4 + (threadIdx.x >> 6);
    const int l   = threadIdx.x & 63;
    const float4* src = reinterpret_cast<const float4*>(feat + (size_t)row * DD);
    float4 v0 = src[l * 2 + 0];
    float4 v1 = src[l * 2 + 1];
    float ss = v0.x*v0.x + v0.y*v0.y + v0.z*v0.z + v0.w*v0.w
             + v1.x*v1.x + v1.y*v1.y + v1.z*v1.z + v1.w*v1.w;
    #pragma unroll
    for (int m = 32; m >= 1; m >>= 1) ss += __shfl_xor(ss, m, 64);
    const float rn = rsqrtf(ss);
    float vals[8] = {v0.x, v0.y, v0.z, v0.w, v1.x, v1.y, v1.z, v1.w};
    ushort u[8];
    #pragma unroll
    for (int j = 0; j < 8; ++j) u[j] = f2bf(vals[j] * rn);
    *reinterpret_cast<short8*>(fnrm + (size_t)row * DD + l * 8) =
        *reinterpret_cast<short8*>(u);
}

// ---------- kernel 2: per-class g_c via ballot scan -> cls_val[c], counts[c] ----
// (verified R13/R14) Sum_pos identity: sum_i spos_i/npos_i = (||g_c||^2-n)/(T(n-1))
__global__ __launch_bounds__(256) void gsum(const ushort* __restrict__ fnrm,
                                            const int* __restrict__ labels,
                                            float* __restrict__ cls_val,
                                            int* __restrict__ counts) {
    __shared__ int   slab[BSZ];          // 32 KB
    __shared__ float gred[4][DD];        // 8 KB
    __shared__ float sq4[4];
    __shared__ int   cc[4];

    const int t = threadIdx.x, w = t >> 6, lam = t & 63;
    for (int i = t; i < BSZ; i += 256) slab[i] = labels[i];
    __syncthreads();

    const int c = blockIdx.x;
    float a[8] = {0.f,0.f,0.f,0.f,0.f,0.f,0.f,0.f};
    int cnt = 0;
    for (int base = w * 2048; base < (w + 1) * 2048; base += 64) {
        const unsigned long long m0 = __ballot(slab[base + lam] == c);
        cnt += (int)__popcll(m0);
        unsigned long long m = m0;
        while (m) {
            const int j = __ffsll((long long)m) - 1; m &= m - 1;
            const short8 v = *reinterpret_cast<const short8*>(
                fnrm + (size_t)(base + j) * DD + lam * 8);
            #pragma unroll
            for (int d = 0; d < 8; ++d) a[d] += bf2f((ushort)v[d]);
        }
    }
    #pragma unroll
    for (int d = 0; d < 8; ++d) gred[w][lam * 8 + d] = a[d];
    if (lam == 0) cc[w] = cnt;
    __syncthreads();

    const float g0 = gred[0][t] + gred[1][t] + gred[2][t] + gred[3][t];
    const float g1 = gred[0][t + 256] + gred[1][t + 256] + gred[2][t + 256] + gred[3][t + 256];
    float sq = g0 * g0 + g1 * g1;
    #pragma unroll
    for (int m = 32; m >= 1; m >>= 1) sq += __shfl_xor(sq, m, 64);
    if (lam == 0) sq4[w] = sq;
    __syncthreads();
    if (t == 0) {
        const float gsq = sq4[0] + sq4[1] + sq4[2] + sq4[3];
        const int   n   = cc[0] + cc[1] + cc[2] + cc[3];
        counts[c]  = n;
        cls_val[c] = (n >= 2) ? (gsq - (float)n) * INV_T / (float)(n - 1) : 0.f;
    }
}

// ---------- kernel 3: sim-GEMM -> denom only. 2-buf, 4 blocks/CU ----------
// 4 waves (2x2), wave = 64x64 out (acc[4][4] = 64 AGPR). BK=32, 16 K-tiles.
// 2 LDS bufs (32 KB) -> 4 blocks/CU. Per iter: vmcnt(0)+barrier (tile it,
// staged one full iter earlier, landed) -> STG(it+1) -> ds_read -> MFMA.
// launch_bounds(256,4): arch VGPR <= 64 (+64 acc = 128/wave at 4 waves/SIMD).
__global__ __launch_bounds__(256, 4) void supcon_main(const ushort* __restrict__ fnrm,
                                                      float* __restrict__ part_denom) {
    __shared__ __align__(16) ushort smem[2 * 8192];    // 32 KB: buf b at b*16384B

    // bijective XCD-contiguous swizzle (2080 = 8 * 260) + upper-tri decode
    const int raw = blockIdx.x;
    const int bid = (raw & 7) * 260 + (raw >> 3);
    int rt = 0, rem = bid;
    while (rem >= NT - rt) { rem -= NT - rt; ++rt; }
    const int ct = rt + rem;
    const bool diag = (ct == rt);

    const int t  = threadIdx.x;
    const int l  = t & 63;
    const int lr = l & 15, grp = l >> 4;
    const int w  = t >> 6;
    const int wr = w >> 1, wc = w & 1;    // 2x2 wave grid; wave = 64x64 out
    const int rowBase = rt * 128, colBase = ct * 128;

    // staging: thread t fills phys chunk t (rows 0-63) and t+256 (rows 64-127).
    // logical chunk = pc ^ ((row>>1)&3), invariant under row+64; applied by
    // pre-swizzling the global source (LDS dest stays linear).
    const int srow = t >> 2;
    const int slc  = (t & 3) ^ ((srow >> 1) & 3);
    const ushort* gA = fnrm + (size_t)(rowBase + srow) * DD + slc * 8;
    const ushort* gB = fnrm + (size_t)(colBase + srow) * DD + slc * 8;
    char* S = (char*)smem;
    const int t16 = t * 16;

    #define STG(kt, b) { \
        gload16(gA + (kt) * 32,           S + (b) * 16384 +         t16); \
        gload16(gA + (kt) * 32 + 64 * DD, S + (b) * 16384 +  4096 + t16); \
        gload16(gB + (kt) * 32,           S + (b) * 16384 +  8192 + t16); \
        gload16(gB + (kt) * 32 + 64 * DD, S + (b) * 16384 + 12288 + t16); }

    // ds_read byte addrs (loop-invariant); buf & frag are immediates.
    const int swz = ((grp ^ ((lr >> 1) & 3)) << 4);
    const int va  = (wr * 64 + lr) * 64 + swz;          // + b*16384 + fa*1024
    const int vb  = 8192 + (wc * 64 + lr) * 64 + swz;   // + b*16384 + fb*1024

    f32x4 acc[4][4];
    #pragma unroll
    for (int i = 0; i < 4; ++i)
        #pragma unroll
        for (int j = 0; j < 4; ++j) acc[i][j] = f32x4{0.f, 0.f, 0.f, 0.f};

    STG(0, 0)

    #pragma unroll
    for (int it = 0; it < 16; ++it) {
        const int b = it & 1;
        asm volatile("s_waitcnt vmcnt(0)" ::: "memory");  // tile it landed
        __builtin_amdgcn_s_barrier();                     // ...for all waves
        if (it < 15) STG(it + 1, b ^ 1)                   // full-iter issue->wait gap

        short8 aF[4], bF[4];
        DSR(aF[0], va, (b * 16384) + 0)     DSR(aF[1], va, (b * 16384) + 1024)
        DSR(aF[2], va, (b * 16384) + 2048)  DSR(aF[3], va, (b * 16384) + 3072)
        DSR(bF[0], vb, (b * 16384) + 0)     DSR(bF[1], vb, (b * 16384) + 1024)
        DSR(bF[2], vb, (b * 16384) + 2048)  DSR(bF[3], vb, (b * 16384) + 3072)
        asm volatile("s_waitcnt lgkmcnt(0)");
        __builtin_amdgcn_sched_barrier(0);   // rule #18
        __builtin_amdgcn_s_setprio(1);
        #pragma unroll
        for (int fa = 0; fa < 4; ++fa)
            #pragma unroll
            for (int fb = 0; fb < 4; ++fb)
                acc[fa][fb] = __builtin_amdgcn_mfma_f32_16x16x32_bf16(
                    aF[fa], bF[fb], acc[fa][fb], 0, 0, 0);
        __builtin_amdgcn_s_setprio(0);
    }
    #undef STG

    // ---- lean epilogue: e = exp(sim - m); row & col denom sums only ----
    __syncthreads();
    float* red  = reinterpret_cast<float*>(smem);          // [128 row][2 wc]
    float* cred = reinterpret_cast<float*>(smem) + 256;    // [128 col][2 wr]

    float cdv[4] = {0.f, 0.f, 0.f, 0.f};
    #pragma unroll
    for (int fa = 0; fa < 4; ++fa) {
        #pragma unroll
        for (int r = 0; r < 4; ++r) {
            const int row_l = wr * 64 + fa * 16 + grp * 4 + r;
            const int grow  = rowBase + row_l;
            float dsum = 0.f;
            #pragma unroll
            for (int fb = 0; fb < 4; ++fb) {
                const int col_l = wc * 64 + fb * 16 + lr;
                const float e  = __expf(acc[fa][fb][r] * INV_T - INV_T);
                const float ev = ((colBase + col_l) != grow) ? e : 0.f;
                dsum += ev; cdv[fb] += ev;
            }
            ROWSUM16(dsum)
            if (lr == 0) red[row_l * 2 + wc] = dsum;
        }
    }
    #pragma unroll
    for (int fb = 0; fb < 4; ++fb) {      // col-side: reduce over grp lanes
        cdv[fb] += __shfl_xor(cdv[fb], 16, 64);
        cdv[fb] += __shfl_xor(cdv[fb], 32, 64);
    }
    if (grp == 0) {
        #pragma unroll
        for (int fb = 0; fb < 4; ++fb)
            cred[(wc * 64 + fb * 16 + lr) * 2 + wr] = cdv[fb];
    }
    __syncthreads();
    if (t < 128) {                        // row-side: combine 2 wc halves
        const float d = red[t * 2] + red[t * 2 + 1];
        part_denom[(size_t)ct * BSZ + rowBase + t] = d;
    } else if (!diag) {                   // col-side: combine 2 wr halves
        const int c = t - 128;
        const float d = cred[c * 2] + cred[c * 2 + 1];
        part_denom[(size_t)rt * BSZ + colBase + c] = d;
    }
}

// ---------- kernel 4: per-row lse + per-block scalar partials ----------
__global__ __launch_bounds__(256) void row_finalize(const float* __restrict__ part_denom,
                                                    const int* __restrict__ counts,
                                                    const int* __restrict__ labels,
                                                    float* __restrict__ bsum,
                                                    float* __restrict__ bval) {
    __shared__ float s4[4], v4[4];
    const int t = threadIdx.x;
    const int row = blockIdx.x * 256 + t;
    float denom = 0.f;
    for (int k = 0; k < NT; ++k) denom += part_denom[(size_t)k * BSZ + row];
    const bool valid = counts[labels[row]] >= 2;
    float s = valid ? (INV_T + logf(denom + 1e-12f)) : 0.f;
    float v = valid ? 1.f : 0.f;
    #pragma unroll
    for (int m = 32; m >= 1; m >>= 1) { s += __shfl_xor(s, m, 64); v += __shfl_xor(v, m, 64); }
    if ((t & 63) == 0) { s4[t >> 6] = s; v4[t >> 6] = v; }
    __syncthreads();
    if (t == 0) {
        bsum[blockIdx.x] = s4[0] + s4[1] + s4[2] + s4[3];
        bval[blockIdx.x] = v4[0] + v4[1] + v4[2] + v4[3];
    }
}

// ---------- kernel 5: final scalar ----------
__global__ __launch_bounds__(128) void final_reduce(const float* __restrict__ bsum,
                                                    const float* __restrict__ bval,
                                                    const float* __restrict__ cls_val,
                                                    float* __restrict__ out) {
    __shared__ float r2[2], q2[2], p2[2];
    const int t = threadIdx.x;
    float s = (t < 32) ? bsum[t] : 0.f;
    float v = (t < 32) ? bval[t] : 0.f;
    float p = (t < NC) ? cls_val[t] : 0.f;
    #pragma unroll
    for (int m = 32; m >= 1; m >>= 1) {
        s += __shfl_xor(s, m, 64); v += __shfl_xor(v, m, 64); p += __shfl_xor(p, m, 64);
    }
    if ((t & 63) == 0) { r2[t >> 6] = s; q2[t >> 6] = v; p2[t >> 6] = p; }
    __syncthreads();
    if (t == 0) {
        const float S = r2[0] + r2[1], V = q2[0] + q2[1], SP = p2[0] + p2[1];
        out[0] = -(SP - S) / fmaxf(V, 1.f);
    }
}

extern "C" void kernel_launch(void* const* d_in, const int* in_sizes, int n_in,
                              void* d_out, int out_size, void* d_ws, size_t ws_size,
                              hipStream_t stream) {
    const float* feat   = (const float*)d_in[0];
    const int*   labels = (const int*)d_in[1];
    float*       out    = (float*)d_out;

    char* ws = (char*)d_ws;
    ushort* fnrm       = (ushort*)ws;  ws += (size_t)BSZ * DD * 2;   // 8 MB
    float*  part_denom = (float*)ws;   ws += (size_t)NT * BSZ * 4;   // 2 MB
    float*  cls_val    = (float*)ws;   ws += NC * 4 + 288;
    int*    counts     = (int*)ws;     ws += NC * 4 + 288;
    float*  bsum       = (float*)ws;   ws += 32 * 4;
    float*  bval       = (float*)ws;   ws += 32 * 4;

    hipLaunchKernelGGL(norm_rows,    dim3(BSZ / 4), dim3(256),  0, stream, feat, fnrm);
    hipLaunchKernelGGL(gsum,         dim3(NC),      dim3(256),  0, stream,
                       fnrm, labels, cls_val, counts);
    hipLaunchKernelGGL(supcon_main,  dim3(NBLK),    dim3(256),  0, stream,
                       fnrm, part_denom);
    hipLaunchKernelGGL(row_finalize, dim3(BSZ/256), dim3(256),  0, stream,
                       part_denom, counts, labels, bsum, bval);
    hipLaunchKernelGGL(final_reduce, dim3(1),       dim3(128),  0, stream,
                       bsum, bval, cls_val, out);
}